// Round 1
// baseline (146.396 us; speedup 1.0000x reference)
//
#include <hip/hip_runtime.h>
#include <cstddef>

#define SEQ    1024
#define CH     64
#define UNITS  32
#define WIDTH  64
#define HALFW  32
#define BATCH  4
#define EPS    1e-7f

// Kernel 1: q[b][u][s] = sum_c x[b][c][s] * Wt[u][c]; same for k with Wx.
// Thread id = (b*UNITS + u)*SEQ + s  -> consecutive lanes = consecutive s
// so each x[b][c][s] read is coalesced (64 consecutive floats per wave)
// and q/k writes are coalesced.
__global__ __launch_bounds__(256) void qk_kernel(
    const float* __restrict__ x, const float* __restrict__ Wt,
    const float* __restrict__ Wx, float* __restrict__ q, float* __restrict__ k)
{
    int tid = blockIdx.x * blockDim.x + threadIdx.x;
    int s  = tid & (SEQ - 1);
    int bu = tid >> 10;             // b*UNITS + u
    int u  = bu & (UNITS - 1);
    int b  = bu >> 5;

    const float* xb = x + (size_t)b * CH * SEQ + s;
    const float* wt = Wt + u * CH;
    const float* wx = Wx + u * CH;
    float qa = 0.f, ka = 0.f;
#pragma unroll
    for (int c = 0; c < CH; ++c) {
        float xv = xb[(size_t)c * SEQ];
        qa = fmaf(xv, wt[c], qa);
        ka = fmaf(xv, wx[c], ka);
    }
    q[tid] = qa;
    k[tid] = ka;
}

// Kernel 2: one wave per (b, s). Lane j handles key t = s - 32 + j.
// Computes windowed additive score, wave-softmax, writes full a-row
// (zeros outside window) and v[b, :, s] (lane = channel).
__global__ __launch_bounds__(64) void attn_kernel(
    const float* __restrict__ x,
    const float* __restrict__ q, const float* __restrict__ k,
    const float* __restrict__ Wa_w, const float* __restrict__ Wa_b,
    const float* __restrict__ bh, float* __restrict__ out)
{
    int bs   = blockIdx.x;          // b*SEQ + s
    int s    = bs & (SEQ - 1);
    int b    = bs >> 10;
    int lane = threadIdx.x;

    int lower = s - HALFW;
    int t     = lower + lane;
    bool valid = (t >= 0) && (t < SEQ);
    int tc    = valid ? t : 0;

    const float* qb = q + (size_t)b * UNITS * SEQ;
    const float* kb = k + (size_t)b * UNITS * SEQ;

    float e = Wa_b[0];
#pragma unroll
    for (int u = 0; u < UNITS; ++u) {
        float qu = qb[u * SEQ + s];    // wave-uniform
        float ku = kb[u * SEQ + tc];   // coalesced across lanes
        float z  = qu + ku + bh[u];
        float ex = __expf(2.f * z);
        float th = 1.f - 2.f / (ex + 1.f);   // tanh(z), overflow-safe
        e = fmaf(th, Wa_w[u], e);
    }
    if (!valid) e = -INFINITY;

    // wave max over 64 lanes
    float m = e;
#pragma unroll
    for (int off = 32; off >= 1; off >>= 1)
        m = fmaxf(m, __shfl_xor(m, off));

    float p = valid ? __expf(e - m) : 0.f;
    float ssum = p;
#pragma unroll
    for (int off = 32; off >= 1; off >>= 1)
        ssum += __shfl_xor(ssum, off);

    float a = p / (ssum + EPS);

    __shared__ float a_s[WIDTH];
    a_s[lane] = a;
    __syncthreads();

    // write full a row: a[b][s][0..S) with zeros outside window (coalesced)
    float* arow = out + (size_t)BATCH * CH * SEQ + (size_t)bs * SEQ;
#pragma unroll
    for (int j = 0; j < SEQ / 64; ++j) {
        int idx = j * 64 + lane;
        int d   = idx - lower;
        float val = (d >= 0 && d < WIDTH) ? a_s[d] : 0.f;
        arow[idx] = val;
    }

    // v[b][c][s] = sum_j a_s[j] * x[b][c][lower+j]; lane = c
    int c = lane;
    const float* xb = x + ((size_t)b * CH + c) * SEQ;
    float acc = 0.f;
#pragma unroll
    for (int j = 0; j < WIDTH; ++j) {
        int tt  = lower + j;
        int ttc = tt < 0 ? 0 : (tt >= SEQ ? SEQ - 1 : tt);
        acc = fmaf(a_s[j], xb[ttc], acc);   // a_s[j]==0 when tt invalid
    }
    out[((size_t)b * CH + c) * SEQ + s] = acc;
}

extern "C" void kernel_launch(void* const* d_in, const int* in_sizes, int n_in,
                              void* d_out, int out_size, void* d_ws, size_t ws_size,
                              hipStream_t stream) {
    const float* x    = (const float*)d_in[0];
    const float* Wt   = (const float*)d_in[1];
    const float* Wx   = (const float*)d_in[2];
    const float* Wa_w = (const float*)d_in[3];
    const float* Wa_b = (const float*)d_in[4];
    const float* bh   = (const float*)d_in[5];
    float* out = (float*)d_out;

    float* q = (float*)d_ws;                       // (B, U, S)
    float* kk = q + (size_t)BATCH * UNITS * SEQ;   // (B, U, S)

    int n_qk = BATCH * UNITS * SEQ;                // 131072 threads
    qk_kernel<<<n_qk / 256, 256, 0, stream>>>(x, Wt, Wx, q, kk);
    attn_kernel<<<BATCH * SEQ, 64, 0, stream>>>(x, q, kk, Wa_w, Wa_b, bh, out);
}

// Round 2
// 79.557 us; speedup vs baseline: 1.8401x; 1.8401x over previous
//
#include <hip/hip_runtime.h>
#include <cstddef>
#include <cmath>

#define SEQ    1024
#define CH     64
#define UNITS  32
#define WIDTH  64
#define HALFW  32
#define BATCH  4
#define EPS    1e-7f

#define TS     8          // s-tile per block
#define TT     72         // t-extent staged: TS + 63, padded to 72
#define XS     73         // LDS row stride for xt/kt (pad to break pow2)
#define SCS    65         // LDS row stride for score tile

// ---------------- Kernel 1: q/k projections, float4 over s ----------------
// block = one (b,u), 256 threads x 4 s each. x loads coalesced 16B/lane,
// Wt/Wx rows wave-uniform (scalar loads). Full unroll -> deep vmcnt pipeline.
__global__ __launch_bounds__(256) void qk_kernel(
    const float* __restrict__ x, const float* __restrict__ Wt,
    const float* __restrict__ Wx, float* __restrict__ q, float* __restrict__ k)
{
    int bu = blockIdx.x;                 // b*UNITS + u
    int u  = bu & (UNITS - 1);
    int b  = bu >> 5;
    int s4 = (int)threadIdx.x << 2;

    const float* wt = Wt + u * CH;
    const float* wx = Wx + u * CH;
    const float* xb = x + (size_t)b * CH * SEQ + s4;

    float4 qa = {0.f, 0.f, 0.f, 0.f};
    float4 ka = {0.f, 0.f, 0.f, 0.f};
#pragma unroll
    for (int c = 0; c < CH; ++c) {
        float4 xv = *reinterpret_cast<const float4*>(xb + (size_t)c * SEQ);
        float wtc = wt[c], wxc = wx[c];
        qa.x = fmaf(xv.x, wtc, qa.x); qa.y = fmaf(xv.y, wtc, qa.y);
        qa.z = fmaf(xv.z, wtc, qa.z); qa.w = fmaf(xv.w, wtc, qa.w);
        ka.x = fmaf(xv.x, wxc, ka.x); ka.y = fmaf(xv.y, wxc, ka.y);
        ka.z = fmaf(xv.z, wxc, ka.z); ka.w = fmaf(xv.w, wxc, ka.w);
    }
    size_t o = (size_t)bu * SEQ + s4;
    *reinterpret_cast<float4*>(q + o) = qa;
    *reinterpret_cast<float4*>(k + o) = ka;
}

// ---------------- Kernel 2: windowed scores + softmax + a-write + v --------
// block = 256 threads, one (b, 8-s tile). LDS-staged x/k/q tiles.
__global__ __launch_bounds__(256) void attn_kernel(
    const float* __restrict__ x,
    const float* __restrict__ q, const float* __restrict__ k,
    const float* __restrict__ Wa_w, const float* __restrict__ Wa_b,
    const float* __restrict__ bh, float* __restrict__ out)
{
    __shared__ float xt[CH * XS];       // x[b][c][t0+tt]
    __shared__ float kt[UNITS * XS];    // k[b][u][t0+tt]
    __shared__ float qt[UNITS * TS];    // q[b][u][s0+sl]
    __shared__ float sc[TS * SCS];      // scores -> a
    __shared__ float wa_s[UNITS], bh_s[UNITS];
    __shared__ float wab_s;

    int tid = threadIdx.x;
    int blk = blockIdx.x;
    int b   = blk >> 7;                 // SEQ/TS = 128 tiles per batch
    int s0  = (blk & 127) << 3;
    int t0  = s0 - HALFW;

    const float* xb = x + (size_t)b * CH * SEQ;
    const float* qb = q + (size_t)b * UNITS * SEQ;
    const float* kb = k + (size_t)b * UNITS * SEQ;

    // ---- stage ----
    {
        int u = tid >> 3, sl = tid & 7;
        qt[u * TS + sl] = qb[u * SEQ + s0 + sl];
    }
    if (tid < UNITS) { wa_s[tid] = Wa_w[tid]; bh_s[tid] = bh[tid]; }
    if (tid == 0)    { wab_s = Wa_b[0]; }
#pragma unroll
    for (int i = 0; i < 9; ++i) {       // 32*72 = 2304 = 9*256
        int idx = i * 256 + tid;
        int u = idx / TT, tt = idx - u * TT;
        int t = t0 + tt; t = t < 0 ? 0 : (t >= SEQ ? SEQ - 1 : t);
        kt[u * XS + tt] = kb[u * SEQ + t];
    }
#pragma unroll
    for (int i = 0; i < 18; ++i) {      // 64*72 = 4608 = 18*256
        int idx = i * 256 + tid;
        int c = idx / TT, tt = idx - c * TT;
        int t = t0 + tt; t = t < 0 ? 0 : (t >= SEQ ? SEQ - 1 : t);
        xt[c * XS + tt] = xb[c * SEQ + t];
    }
    __syncthreads();

    // ---- scores: thread -> (sl = tid>>5, tl in {tid&31, +32}) ----
    {
        int sl = tid >> 5, tlg = tid & 31;
        float e0 = wab_s, e1 = wab_s;
#pragma unroll
        for (int u = 0; u < UNITS; ++u) {
            float qv = qt[u * TS + sl] + bh_s[u];
            float k0 = kt[u * XS + sl + tlg];
            float k1 = kt[u * XS + sl + tlg + 32];
            float wa = wa_s[u];
            float z0 = qv + k0, z1 = qv + k1;
            // tanh(z) = 1 - 2/(exp(2z)+1), overflow-safe
            float th0 = 1.f - 2.f * __builtin_amdgcn_rcpf(__expf(2.f * z0) + 1.f);
            float th1 = 1.f - 2.f * __builtin_amdgcn_rcpf(__expf(2.f * z1) + 1.f);
            e0 = fmaf(th0, wa, e0);
            e1 = fmaf(th1, wa, e1);
        }
        int ta = t0 + sl + tlg, tb = t0 + sl + tlg + 32;
        if (ta < 0 || ta >= SEQ) e0 = -INFINITY;
        if (tb < 0 || tb >= SEQ) e1 = -INFINITY;
        sc[sl * SCS + tlg]      = e0;
        sc[sl * SCS + tlg + 32] = e1;
    }
    __syncthreads();

    // ---- softmax: each 32-lane group owns one row (2 elements/lane) ----
    {
        int lane = tid & 63, wv = tid >> 6;
        int row  = wv * 2 + (lane >> 5);
        int l32  = lane & 31;
        float e0 = sc[row * SCS + l32];
        float e1 = sc[row * SCS + l32 + 32];
        float m = fmaxf(e0, e1);
#pragma unroll
        for (int off = 16; off >= 1; off >>= 1) m = fmaxf(m, __shfl_xor(m, off));
        float p0 = __expf(e0 - m), p1 = __expf(e1 - m);
        float ssum = p0 + p1;
#pragma unroll
        for (int off = 16; off >= 1; off >>= 1) ssum += __shfl_xor(ssum, off);
        float inv = __builtin_amdgcn_rcpf(ssum + EPS);
        sc[row * SCS + l32]      = p0 * inv;
        sc[row * SCS + l32 + 32] = p1 * inv;
    }
    __syncthreads();

    // ---- a-write: 8 rows x 1024 floats, float4 per thread per row ----
    float* arow = out + (size_t)BATCH * CH * SEQ + ((size_t)(b * SEQ + s0)) * SEQ;
    int i0 = tid << 2;
#pragma unroll
    for (int r = 0; r < TS; ++r) {
        int lowerAbs = s0 + r - HALFW;
        int d = i0 - lowerAbs;          // window offset of component .x
        float4 v4 = {0.f, 0.f, 0.f, 0.f};
        if (d > -4 && d < WIDTH) {
            const float* row = sc + r * SCS;
            if (d >= 0     && d     < WIDTH) v4.x = row[d];
            if (d + 1 >= 0 && d + 1 < WIDTH) v4.y = row[d + 1];
            if (d + 2 >= 0 && d + 2 < WIDTH) v4.z = row[d + 2];
            if (d + 3 >= 0 && d + 3 < WIDTH) v4.w = row[d + 3];
        }
        *reinterpret_cast<float4*>(arow + (size_t)r * SEQ + i0) = v4;
    }

    // ---- v: thread -> (sl = tid&7, c = 2*(tid>>3)+{0,1}) ----
    {
        int slv = tid & 7, c0 = (tid >> 3) << 1;
        float acc0 = 0.f, acc1 = 0.f;
        const float* x0 = xt + c0 * XS + slv;
        const float* x1 = x0 + XS;
        const float* ar = sc + slv * SCS;
#pragma unroll
        for (int j = 0; j < WIDTH; ++j) {
            float av = ar[j];
            acc0 = fmaf(av, x0[j], acc0);
            acc1 = fmaf(av, x1[j], acc1);
        }
        out[((size_t)(b * CH + c0)) * SEQ + s0 + slv]     = acc0;
        out[((size_t)(b * CH + c0 + 1)) * SEQ + s0 + slv] = acc1;
    }
}

extern "C" void kernel_launch(void* const* d_in, const int* in_sizes, int n_in,
                              void* d_out, int out_size, void* d_ws, size_t ws_size,
                              hipStream_t stream) {
    const float* x    = (const float*)d_in[0];
    const float* Wt   = (const float*)d_in[1];
    const float* Wx   = (const float*)d_in[2];
    const float* Wa_w = (const float*)d_in[3];
    const float* Wa_b = (const float*)d_in[4];
    const float* bh   = (const float*)d_in[5];
    float* out = (float*)d_out;

    float* q  = (float*)d_ws;                      // (B, U, S)
    float* kk = q + (size_t)BATCH * UNITS * SEQ;   // (B, U, S)

    qk_kernel<<<BATCH * UNITS, 256, 0, stream>>>(x, Wt, Wx, q, kk);
    attn_kernel<<<BATCH * (SEQ / TS), 256, 0, stream>>>(x, q, kk, Wa_w, Wa_b, bh, out);
}